// Round 1
// 6868.672 us; speedup vs baseline: 1.1171x; 1.1171x over previous
//
#include <hip/hip_runtime.h>
#include <cstddef>

#define F 128
#define H 512
#define RB 16          // rows per block -> grid = 256 (one block per CU)
#define NSTEPS 100
#define W1S 136        // W1t row stride (elements, 16B-aligned)
#define ABS 136        // abuf row stride
#define HS  520        // h buffer row stride (16B-aligned)
#define P3S 132        // p3buf row stride (f32, padded: 132%32=4 -> 2-way max)

typedef short short8 __attribute__((ext_vector_type(8)));
typedef float f32x4  __attribute__((ext_vector_type(4)));
typedef float f32x2  __attribute__((ext_vector_type(2)));

__device__ __forceinline__ unsigned short f2bf(float f) {
    union { float f; unsigned int u; } v; v.f = f;
    unsigned int u = v.u;
    return (unsigned short)((u + 0x7FFFu + ((u >> 16) & 1u)) >> 16);  // RTNE
}
__device__ __forceinline__ float bf2f(unsigned short h) {
    union { unsigned int u; float f; } v; v.u = ((unsigned int)h) << 16;
    return v.f;
}
__device__ __forceinline__ float silu_f(float v) {
    float e = __expf(-v);
    return v * __builtin_amdgcn_rcpf(1.0f + e);
}

// ---- prep: transpose weights to bf16 B^T layout in workspace -------------
__global__ void prep_weights(const float* __restrict__ W1,
                             const float* __restrict__ W2,
                             const float* __restrict__ W3,
                             unsigned short* __restrict__ ws) {
    unsigned short* W1t = ws;
    unsigned short* W2t = ws + 512 * W1S;
    unsigned short* W3t = W2t + 512 * 512;
    int stride = gridDim.x * blockDim.x;
    int t0 = blockIdx.x * blockDim.x + threadIdx.x;
    for (int i = t0; i < 512 * W1S; i += stride) {
        int n = i / W1S, k = i - n * W1S;
        W1t[i] = (k < 129) ? f2bf(W1[k * 512 + n]) : (unsigned short)0;
    }
    for (int i = t0; i < 512 * 512; i += stride) {
        int n = i >> 9, k = i & 511;
        W2t[i] = f2bf(W2[k * 512 + n]);
    }
    for (int i = t0; i < 128 * 512; i += stride) {
        int c = i >> 9, k = i & 511;
        W3t[i] = f2bf(W3[k * 128 + c]);
    }
}

// ---- main persistent kernel: 1024 threads = 16 waves, one block per CU ---
// Wave w owns h-columns [w*32, w*32+32) in layers 1/2. ALL of W2 (512 KB)
// is held in the CU's register file: 16 waves x 128 VGPR (short8 w2f[2][16])
// -> zero steady-state global reads. Layer 3 is split-K across wave pairs
// (w, w+8), partials combined via an f32 LDS tile that also stages the
// coalesced traj store.
__global__ __launch_bounds__(1024, 1) void ode_kernel(
    const float* __restrict__ x_in,
    const float* __restrict__ b1,
    const float* __restrict__ b2,
    const float* __restrict__ b3,
    const unsigned short* __restrict__ ws,
    float* __restrict__ traj) {

    __shared__ __attribute__((aligned(16))) unsigned short abuf[RB * ABS];   // bf16 state
    __shared__ __attribute__((aligned(16))) unsigned short h1buf[RB * HS];
    __shared__ __attribute__((aligned(16))) unsigned short h2buf[RB * HS];
    __shared__ __attribute__((aligned(16))) float p3buf[RB * P3S];           // L3 partials / f32 out tile

    const unsigned short* W1t = ws;
    const unsigned short* W2t = ws + 512 * W1S;
    const unsigned short* W3t = W2t + 512 * 512;

    const int tid  = threadIdx.x;
    const int wave = tid >> 6;          // 0..15
    const int lane = tid & 63;
    const int l15  = lane & 15;
    const int q    = lane >> 4;         // quad 0..3
    const int rowbase = blockIdx.x * RB;

    // ---- layer-1 weight fragments + biases (constant) ----
    const int ncol = wave * 32 + l15;   // layer1/2 n-col base for nt=0
    short8 w1f[2][4];
    float  b1v[2], t1v[2], b2v[2];
#pragma unroll
    for (int nt = 0; nt < 2; ++nt) {
        const unsigned short* wrow = W1t + (ncol + nt * 16) * W1S;
#pragma unroll
        for (int kt = 0; kt < 4; ++kt)
            w1f[nt][kt] = *(const short8*)(wrow + kt * 32 + q * 8);
        t1v[nt] = bf2f(wrow[128]);
        b1v[nt] = b1[ncol + nt * 16];
        b2v[nt] = b2[ncol + nt * 16];
    }

    // ---- W2 resident in registers: 128 VGPR/lane, loaded ONCE ----
    short8 w2f[2][16];
    {
        const unsigned short* wb = W2t + (size_t)ncol * 512 + q * 8;
#pragma unroll
        for (int nt = 0; nt < 2; ++nt)
#pragma unroll
            for (int kt = 0; kt < 16; ++kt)
                w2f[nt][kt] = *(const short8*)(wb + nt * (16 * 512) + kt * 32);
    }

    // ---- layer-3: wave pair (cg, kh) -> col-group cg, K-half kh ----
    const int cg = wave & 7;            // output col group (16 cols)
    const int kh = wave >> 3;           // K half: kt in [kh*8, kh*8+8)
    const int cown = cg * 16 + l15;     // layer-3 output column
    short8 w3f[8];
    {
        const unsigned short* wrow = W3t + cown * 512 + kh * 256;
#pragma unroll
        for (int j = 0; j < 8; ++j)
            w3f[j] = *(const short8*)(wrow + j * 32 + q * 8);
    }
    const float b3v = b3[cown];

    float xreg[4]   = {0.f, 0.f, 0.f, 0.f};   // RK4 state (kh==0 waves only)
    float accreg[4] = {0.f, 0.f, 0.f, 0.f};

    // phase 0: load x, emit traj[0], fill abuf
    if (kh == 0) {
#pragma unroll
        for (int i = 0; i < 4; ++i) {
            int r = q * 4 + i;
            float v = x_in[(rowbase + r) * F + cown];
            xreg[i] = v;
            traj[(rowbase + r) * F + cown] = v;
            abuf[r * ABS + cown] = f2bf(v);
        }
    }
    __syncthreads();

#pragma unroll 1
    for (int s = 0; s < NSTEPS - 1; ++s) {
        const float t0  = (float)s * (1.0f / 99.0f);
        const float tn  = (float)(s + 1) * (1.0f / 99.0f);
        const float dt  = tn - t0;
        const float hlf = 0.5f * dt;
        const float c16 = dt * (1.0f / 6.0f);
        const float c13 = dt * (1.0f / 3.0f);

#pragma unroll 1
        for (int e = 0; e < 4; ++e) {
            const float te = (e == 0) ? t0 : ((e == 3) ? tn : (t0 + hlf));

            // ---- layer 1: h1 = silu([x,t] @ W1 + b1), K=128, regs
            {
                short8 af[4];
#pragma unroll
                for (int kt = 0; kt < 4; ++kt)
                    af[kt] = *(const short8*)(abuf + l15 * ABS + kt * 32 + q * 8);
#pragma unroll
                for (int nt = 0; nt < 2; ++nt) {
                    f32x4 a = {0.f, 0.f, 0.f, 0.f};
#pragma unroll
                    for (int kt = 0; kt < 4; ++kt)
                        a = __builtin_amdgcn_mfma_f32_16x16x32_bf16(af[kt], w1f[nt][kt], a, 0, 0, 0);
                    const float bb = b1v[nt] + te * t1v[nt];
                    const int n = ncol + nt * 16;
#pragma unroll
                    for (int i = 0; i < 4; ++i)
                        h1buf[(q * 4 + i) * HS + n] = f2bf(silu_f(a[i] + bb));
                }
            }
            __syncthreads();

            // ---- layer 2: h2 = silu(h1 @ W2 + b2), K=512, W2 IN REGISTERS
            {
                f32x4 acc2[2];
                acc2[0] = (f32x4){0.f, 0.f, 0.f, 0.f};
                acc2[1] = (f32x4){0.f, 0.f, 0.f, 0.f};
#pragma unroll
                for (int kt = 0; kt < 16; ++kt) {
                    short8 af2 = *(const short8*)(h1buf + l15 * HS + kt * 32 + q * 8);
                    acc2[0] = __builtin_amdgcn_mfma_f32_16x16x32_bf16(af2, w2f[0][kt], acc2[0], 0, 0, 0);
                    acc2[1] = __builtin_amdgcn_mfma_f32_16x16x32_bf16(af2, w2f[1][kt], acc2[1], 0, 0, 0);
                }
#pragma unroll
                for (int nt = 0; nt < 2; ++nt) {
                    const int n = ncol + nt * 16;
#pragma unroll
                    for (int i = 0; i < 4; ++i)
                        h2buf[(q * 4 + i) * HS + n] = f2bf(silu_f(acc2[nt][i] + b2v[nt]));
                }
            }
            __syncthreads();

            // ---- layer 3: k = h2 @ W3 + b3 (split-K wave pairs), then RK4
            {
                f32x4 a3 = {0.f, 0.f, 0.f, 0.f};
#pragma unroll
                for (int j = 0; j < 8; ++j) {
                    short8 af = *(const short8*)(h2buf + l15 * HS + (kh * 8 + j) * 32 + q * 8);
                    a3 = __builtin_amdgcn_mfma_f32_16x16x32_bf16(af, w3f[j], a3, 0, 0, 0);
                }
                if (kh) {
#pragma unroll
                    for (int i = 0; i < 4; ++i)
                        p3buf[(q * 4 + i) * P3S + cown] = a3[i];
                }
                __syncthreads();
                if (!kh) {
#pragma unroll
                    for (int i = 0; i < 4; ++i) {
                        const int r = q * 4 + i;
                        const float kv = a3[i] + p3buf[r * P3S + cown] + b3v;
                        if (e == 0) {
                            accreg[i] = xreg[i] + c16 * kv;
                            abuf[r * ABS + cown] = f2bf(xreg[i] + hlf * kv);
                        } else if (e == 1) {
                            accreg[i] += c13 * kv;
                            abuf[r * ABS + cown] = f2bf(xreg[i] + hlf * kv);
                        } else if (e == 2) {
                            accreg[i] += c13 * kv;
                            abuf[r * ABS + cown] = f2bf(xreg[i] + dt * kv);
                        } else {
                            float xn = accreg[i] + c16 * kv;
                            xreg[i] = xn;
                            abuf[r * ABS + cown] = f2bf(xn);
                            p3buf[r * P3S + cown] = xn;   // f32 out tile for coalesced store
                        }
                    }
                }
            }
            __syncthreads();

            // ---- coalesced traj store: 1024 threads x 8 B, full lines ----
            if (e == 3) {
                const int row = tid >> 6;          // 0..15
                const int c2  = (tid & 63) * 2;    // 0..126
                f32x2 v;
                v[0] = p3buf[row * P3S + c2];
                v[1] = p3buf[row * P3S + c2 + 1];
                *(f32x2*)(traj + (size_t)(s + 1) * (4096 * F)
                               + (size_t)(rowbase + row) * F + c2) = v;
            }
        }
    }
}

extern "C" void kernel_launch(void* const* d_in, const int* in_sizes, int n_in,
                              void* d_out, int out_size, void* d_ws, size_t ws_size,
                              hipStream_t stream) {
    const float* x  = (const float*)d_in[0];
    const float* W1 = (const float*)d_in[1];
    const float* b1 = (const float*)d_in[2];
    const float* W2 = (const float*)d_in[3];
    const float* b2 = (const float*)d_in[4];
    const float* W3 = (const float*)d_in[5];
    const float* b3 = (const float*)d_in[6];
    // d_in[7] = n_steps (fixed at 100 per reference; hardcoded)

    unsigned short* wt = (unsigned short*)d_ws;  // needs 794,624 B
    float* traj = (float*)d_out;

    prep_weights<<<256, 256, 0, stream>>>(W1, W2, W3, wt);
    ode_kernel<<<4096 / RB, 1024, 0, stream>>>(x, b1, b2, b3, wt, traj);
}